// Round 1
// baseline (290.882 us; speedup 1.0000x reference)
//
#include <hip/hip_runtime.h>

// FitzHugh-Nagumo RK4, one thread per trajectory.
// B = 4096 trajectories, num_steps = out_size / (2*B) (2048).
// Output layout: out[(s*B + i)*2 + {0,1}] = (x, y)  -> one float2 per (s,i).
//
// Regime: latency-bound on the per-step dependent VALU chain (steps are
// sequential). 64 blocks x 64 threads spreads the 64 waves across CUs so
// each wave owns its SIMD's issue slots.

__global__ __launch_bounds__(64, 1) void fhn_rk4_kernel(
    const float* __restrict__ x0, const float* __restrict__ y0,
    const float* __restrict__ pa, const float* __restrict__ pb,
    const float* __restrict__ pc, float2* __restrict__ out,
    int B, int num_steps)
{
    const int i = blockIdx.x * 64 + threadIdx.x;
    if (i >= B) return;

    const float a = pa[0];
    const float b = pb[0];
    const float c = pc[0];

    const float dt    = 0.1f;
    const float half  = 0.05f;        // STEP * 0.5 (exact in f32)
    const float dt6   = 0.1f / 6.0f;  // STEP / 6, folded once in f32 (matches np)
    const float third = 1.0f / 3.0f;
    const float nic   = -(1.0f / c);  // -(1/c), computed once outside the loop

    float x = x0[i];
    float y = y0[i];

    float2* o = out + i;
    *o = make_float2(x, y);   // step 0 = initial condition
    o += B;

    for (int s = 1; s < num_steps; ++s, o += B) {
        float k1x = c * (x + y - x * x * x * third);
        float k1y = nic * (x + b * y - a);

        float x2 = x + k1x * half;
        float y2 = y + k1y * half;
        float k2x = c * (x2 + y2 - x2 * x2 * x2 * third);
        float k2y = nic * (x2 + b * y2 - a);

        float x3 = x + k2x * half;
        float y3 = y + k2y * half;
        float k3x = c * (x3 + y3 - x3 * x3 * x3 * third);
        float k3y = nic * (x3 + b * y3 - a);

        float x4 = x + k3x * dt;
        float y4 = y + k3y * dt;
        float k4x = c * (x4 + y4 - x4 * x4 * x4 * third);
        float k4y = nic * (x4 + b * y4 - a);

        x = x + (k1x + 2.0f * k2x + 2.0f * k3x + k4x) * dt6;
        y = y + (k1y + 2.0f * k2y + 2.0f * k3y + k4y) * dt6;

        *o = make_float2(x, y);
    }
}

extern "C" void kernel_launch(void* const* d_in, const int* in_sizes, int n_in,
                              void* d_out, int out_size, void* d_ws, size_t ws_size,
                              hipStream_t stream) {
    const float* x0 = (const float*)d_in[0];
    const float* y0 = (const float*)d_in[1];
    const float* pa = (const float*)d_in[2];
    const float* pb = (const float*)d_in[3];
    const float* pc = (const float*)d_in[4];
    // d_in[5] is num_steps (int, on device); derive it on host instead:
    const int B = in_sizes[0];
    const int num_steps = out_size / (2 * B);

    float2* out = (float2*)d_out;

    const int block = 64;
    const int grid = (B + block - 1) / block;
    fhn_rk4_kernel<<<grid, block, 0, stream>>>(x0, y0, pa, pb, pc, out, B, num_steps);
}

// Round 2
// 262.704 us; speedup vs baseline: 1.1073x; 1.1073x over previous
//
#include <hip/hip_runtime.h>
#include <math.h>

// FitzHugh-Nagumo RK4, one thread per trajectory. Latency-bound on the
// sequential per-step dependence chain (2047 steps). This version minimizes
// the dependent-op count per step:
//   per stage:  x_next = fma(-h*c/3, x^3, fma(h*c, x+y, x))   (3 dep ops)
//   k-values for the final RK4 sum are computed OFF the critical path.
// Critical path ~12 FMA-class ops/step (was ~28 in round 1).

__global__ __launch_bounds__(64) void fhn_rk4_kernel(
    const float* __restrict__ x0, const float* __restrict__ y0,
    const float* __restrict__ pa, const float* __restrict__ pb,
    const float* __restrict__ pc, float2* __restrict__ out,
    int B, int num_steps)
{
    const int i = blockIdx.x * 64 + threadIdx.x;
    if (i >= B) return;

    const float a = pa[0];
    const float b = pb[0];
    const float c = pc[0];

    const float dt   = 0.1f;
    const float half = 0.05f;
    const float dt6  = 0.1f / 6.0f;

    // hoisted derived constants (computed once, off the loop)
    const float cc3   = c * (1.0f / 3.0f);   // c/3
    const float nic   = -1.0f / c;           // -(1/c)
    const float anc   = a / c;               // +a/c  (so k_y = nic*(x+b*y) + anc)
    const float hc    = half * c;
    const float hcc3  = half * cc3;
    const float hnic  = half * nic;
    const float hanc  = half * anc;
    const float dc    = dt * c;
    const float dcc3  = dt * cc3;
    const float dnic  = dt * nic;
    const float danc  = dt * anc;
    const float dt6_2 = 2.0f * dt6;
    const float d6c   = dt6 * c;
    const float d6cc3 = dt6 * cc3;
    const float d6nic = dt6 * nic;
    const float d6anc = dt6 * anc;

    float x = x0[i];
    float y = y0[i];

    float2* o = out + i;
    *o = make_float2(x, y);   // step 0 = initial condition
    o += B;

#pragma unroll 2
    for (int s = 1; s < num_steps; ++s, o += B) {
        // ---- stage 1 (state: x, y) ----
        const float s1 = x + y;
        const float p1 = x * x;
        const float q1 = p1 * x;               // x^3
        const float v1 = fmaf(b, y, x);        // x + b*y
        const float k1x = fmaf(-cc3, q1, c * s1);      // off critical path
        const float k1y = fmaf(nic, v1, anc);          // off critical path
        const float x2 = fmaf(-hcc3, q1, fmaf(hc, s1, x));
        const float y2 = fmaf(hnic, v1, y + hanc);

        // ---- stage 2 (state: x2, y2) ----
        const float s2 = x2 + y2;
        const float p2 = x2 * x2;
        const float q2 = p2 * x2;
        const float v2 = fmaf(b, y2, x2);
        const float k2x = fmaf(-cc3, q2, c * s2);
        const float k2y = fmaf(nic, v2, anc);
        const float x3 = fmaf(-hcc3, q2, fmaf(hc, s2, x));
        const float y3 = fmaf(hnic, v2, y + hanc);

        // ---- stage 3 (state: x3, y3, full dt) ----
        const float s3 = x3 + y3;
        const float p3 = x3 * x3;
        const float q3 = p3 * x3;
        const float v3 = fmaf(b, y3, x3);
        const float k3x = fmaf(-cc3, q3, c * s3);
        const float k3y = fmaf(nic, v3, anc);
        const float x4 = fmaf(-dcc3, q3, fmaf(dc, s3, x));
        const float y4 = fmaf(dnic, v3, y + danc);

        // ---- base accumulation (off critical path; ready before q4) ----
        float bx = fmaf(dt6, k1x, x);
        bx = fmaf(dt6_2, k2x, bx);
        bx = fmaf(dt6_2, k3x, bx);
        float by = fmaf(dt6, k1y, y);
        by = fmaf(dt6_2, k2y, by);
        by = fmaf(dt6_2, k3y, by);

        // ---- stage 4 folded directly into the state update ----
        const float s4 = x4 + y4;
        const float p4 = x4 * x4;
        const float q4 = p4 * x4;
        const float v4 = fmaf(b, y4, x4);
        x = fmaf(-d6cc3, q4, fmaf(d6c, s4, bx));   // bx + dt6*k4x
        y = fmaf(d6nic, v4, by + d6anc);           // by + dt6*k4y

        *o = make_float2(x, y);
    }
}

extern "C" void kernel_launch(void* const* d_in, const int* in_sizes, int n_in,
                              void* d_out, int out_size, void* d_ws, size_t ws_size,
                              hipStream_t stream) {
    const float* x0 = (const float*)d_in[0];
    const float* y0 = (const float*)d_in[1];
    const float* pa = (const float*)d_in[2];
    const float* pb = (const float*)d_in[3];
    const float* pc = (const float*)d_in[4];
    const int B = in_sizes[0];
    const int num_steps = out_size / (2 * B);

    float2* out = (float2*)d_out;

    const int block = 64;
    const int grid = (B + block - 1) / block;
    fhn_rk4_kernel<<<grid, block, 0, stream>>>(x0, y0, pa, pb, pc, out, B, num_steps);
}

// Round 3
// 198.805 us; speedup vs baseline: 1.4632x; 1.3214x over previous
//
#include <hip/hip_runtime.h>
#include <math.h>

// FitzHugh-Nagumo RK4, one thread per trajectory, state packed as [x,y]
// so each FMA is a v_pk_fma_f32 (VOP3P, 2 f32 per instruction).
//
// Regime (from rocprof r2): issue-bound on one SIMD per wave (per-SIMD
// VALU issue ~77%); 64 waves, 1 per CU, cannot add more waves. So the
// lever is VALU instruction COUNT per step.
//
// RK4 reformulated without explicit k1..k3:
//   zn = -z/3 + z2/3 + (2/3) z3 + z4/3 + dt6 * f(z4)
// (exact identity: k1=2(x2-x)/dt, k2=2(x3-x)/dt, k3=(x4-x)/dt)

typedef float f2 __attribute__((ext_vector_type(2)));

static __device__ __forceinline__ f2 pkfma(f2 a, f2 b, f2 c) {
    return __builtin_elementwise_fma(a, b, c);
}

__global__ __launch_bounds__(64) void fhn_rk4_kernel(
    const float* __restrict__ x0, const float* __restrict__ y0,
    const float* __restrict__ pa, const float* __restrict__ pb,
    const float* __restrict__ pc, float2* __restrict__ out,
    int B, int num_steps)
{
    const int i = blockIdx.x * 64 + threadIdx.x;
    if (i >= B) return;

    const float a = pa[0];
    const float b = pb[0];
    const float c = pc[0];

    const float dt   = 0.1f;
    const float half = 0.05f;
    const float dt6  = 0.1f / 6.0f;

    const float cc3 = c * (1.0f / 3.0f);
    const float nic = -1.0f / c;
    const float anc = a / c;

    // packed constant vectors (hoisted; live in registers across the loop)
    const f2 Cb   = {1.0f, b};                       // sv = {x+y, x+b*y}
    const f2 Ch   = {half * c, half * nic};          // half-step linear coeffs
    const f2 Cqh  = {-half * cc3, 0.0f};             // half-step cubic coeff
    const f2 Cd   = {dt * c, dt * nic};              // full-step
    const f2 Cqd  = {-dt * cc3, 0.0f};
    const f2 C6   = {dt6 * c, dt6 * nic};            // dt/6-scaled (k4 fold)
    const f2 Cq6  = {-dt6 * cc3, 0.0f};
    const f2 Cha  = {0.0f, half * anc};              // y-base shifts (the -a term)
    const f2 Cda  = {0.0f, dt * anc};
    const f2 C6a  = {0.0f, dt6 * anc};
    const f2 C13  = {1.0f / 3.0f, 1.0f / 3.0f};
    const f2 C23  = {2.0f / 3.0f, 2.0f / 3.0f};
    const f2 Cm13 = {-1.0f / 3.0f, -1.0f / 3.0f};

    f2 z = {x0[i], y0[i]};

    float2* o = out + i;
    *o = make_float2(z.x, z.y);
    o += B;

#pragma unroll 2
    for (int s = 1; s < num_steps; ++s, o += B) {
        const f2 zbh = z + Cha;    // base for half-steps (y gets +h*a/c)
        const f2 zbd = z + Cda;    // base for full step

        // ---- stage 1 ----
        const f2 sv1 = pkfma(z.yy, Cb, z.xx);        // {x+y, x+b*y}
        const float q1 = (z.x * z.x) * z.x;
        const f2 t1 = pkfma(sv1, Ch, zbh);
        const f2 z2 = pkfma((f2){q1, q1}, Cqh, t1);

        // ---- stage 2 ----
        const f2 sv2 = pkfma(z2.yy, Cb, z2.xx);
        const float q2 = (z2.x * z2.x) * z2.x;
        const f2 t2 = pkfma(sv2, Ch, zbh);
        const f2 z3 = pkfma((f2){q2, q2}, Cqh, t2);

        // ---- stage 3 (full dt) ----
        const f2 sv3 = pkfma(z3.yy, Cb, z3.xx);
        const float q3 = (z3.x * z3.x) * z3.x;
        const f2 t3 = pkfma(sv3, Cd, zbd);
        const f2 z4 = pkfma((f2){q3, q3}, Cqd, t3);

        // ---- combination base (off critical path) ----
        f2 acc = pkfma(z2, C13, z * Cm13);
        acc = pkfma(z3, C23, acc);
        acc = pkfma(z4, C13, acc);
        acc = acc + C6a;

        // ---- stage 4 folded into the final update ----
        const f2 sv4 = pkfma(z4.yy, Cb, z4.xx);
        const float q4 = (z4.x * z4.x) * z4.x;
        const f2 t4 = pkfma(sv4, C6, acc);
        z = pkfma((f2){q4, q4}, Cq6, t4);

        *o = make_float2(z.x, z.y);
    }
}

extern "C" void kernel_launch(void* const* d_in, const int* in_sizes, int n_in,
                              void* d_out, int out_size, void* d_ws, size_t ws_size,
                              hipStream_t stream) {
    const float* x0 = (const float*)d_in[0];
    const float* y0 = (const float*)d_in[1];
    const float* pa = (const float*)d_in[2];
    const float* pb = (const float*)d_in[3];
    const float* pc = (const float*)d_in[4];
    const int B = in_sizes[0];
    const int num_steps = out_size / (2 * B);

    float2* out = (float2*)d_out;

    const int block = 64;
    const int grid = (B + block - 1) / block;
    fhn_rk4_kernel<<<grid, block, 0, stream>>>(x0, y0, pa, pb, pc, out, B, num_steps);
}